// Round 1
// baseline (1045.156 us; speedup 1.0000x reference)
//
#include <hip/hip_runtime.h>
#include <math.h>

#define N_NODES 100000
#define N_EDGES 1600000
#define DIM 128
#define EIGD 32
#define CS_EPS 1e-8f

// ---- workspace layout (bytes) ----
// s0:      E floats            [0, 6.4e6)
// ssa:     E float2 (s0,adj*c) [6.4e6, 19.2e6)
// scol:    E int               [19.2e6, 25.6e6)
// count:   N int
// offs:    N+1 int
// cursor:  N int
// me:      N float
// scal:    4 float (Sab,Saa,Sbb,c)
static const size_t OFF_S0     = 0;
static const size_t OFF_SA     = 6400000;
static const size_t OFF_SCOL   = 19200000;
static const size_t OFF_COUNT  = 25600000;
static const size_t OFF_OFFS   = 26000000;
static const size_t OFF_CURSOR = 26400016;
static const size_t OFF_ME     = 26800016;
static const size_t OFF_SCAL   = 27200016;

__global__ void k0_init(const float* __restrict__ motif_w,
                        const int* __restrict__ motif_ids,
                        float* __restrict__ me, int* __restrict__ count,
                        float* __restrict__ scal) {
    int i = blockIdx.x * blockDim.x + threadIdx.x;
    if (i < N_NODES) {
        me[i] = motif_w[motif_ids[i]];
        count[i] = 0;
    }
    if (i < 4) scal[i] = 0.f;
}

// Edge pass: 32 lanes per edge. Computes s0[e] = q.k/sqrt(D) + exp(l0)*eig.eig,
// histograms count[row], accumulates cosine-sim sums.
__global__ void __launch_bounds__(256) k1_edge(
        const float* __restrict__ q, const float* __restrict__ k,
        const float* __restrict__ eigs, const float* __restrict__ lambda0,
        const int* __restrict__ row, const int* __restrict__ col,
        const float* __restrict__ me,
        float* __restrict__ s0, int* __restrict__ count,
        float* __restrict__ scal) {
    const int tid  = threadIdx.x;
    const int l32  = tid & 31;
    const int half = (tid >> 5) & 1;
    const long waves_per_block = blockDim.x >> 6;
    const long gwave = (long)blockIdx.x * waves_per_block + (tid >> 6);
    const long total = (long)gridDim.x * waves_per_block;
    const float inv_sqrt_d = 0.08838834764831843f; // 1/sqrt(128)
    const float el0 = expf(lambda0[0]);

    float sab = 0.f, saa = 0.f, sbb = 0.f;

    for (long base = gwave * 2; base < N_EDGES; base += total * 2) {
        long e = base + half;
        bool valid = (e < N_EDGES);
        float x = 0.f, y = 0.f;
        int r = 0, c = 0;
        if (valid) {
            r = row[e]; c = col[e];
            const float4* qv = (const float4*)(q + (size_t)r * DIM);
            const float4* kv = (const float4*)(k + (size_t)c * DIM);
            float4 a = qv[l32];
            float4 b = kv[l32];
            x = a.x * b.x + a.y * b.y + a.z * b.z + a.w * b.w;
            y = eigs[(size_t)r * EIGD + l32] * eigs[(size_t)c * EIGD + l32];
        }
#pragma unroll
        for (int off = 16; off >= 1; off >>= 1) {
            x += __shfl_xor(x, off);
            y += __shfl_xor(y, off);
        }
        if (valid && l32 == 0) {
            s0[e] = x * inv_sqrt_d + el0 * y;
            atomicAdd(&count[r], 1);
            float mr = me[r], mc = me[c];
            sab += mr * mc; saa += mr * mr; sbb += mc * mc;
        }
    }

    __shared__ float ls[3][8];
    int slot = tid >> 5;  // 8 half-wave leaders per 256-thread block
    if (l32 == 0) { ls[0][slot] = sab; ls[1][slot] = saa; ls[2][slot] = sbb; }
    __syncthreads();
    if (tid == 0) {
        float a = 0.f, b = 0.f, cc = 0.f;
#pragma unroll
        for (int i = 0; i < 8; i++) { a += ls[0][i]; b += ls[1][i]; cc += ls[2][i]; }
        atomicAdd(&scal[0], a);
        atomicAdd(&scal[1], b);
        atomicAdd(&scal[2], cc);
    }
}

// Single block: finalize scalar c = gamma*sim; exclusive-scan count -> offs/cursor.
__global__ void __launch_bounds__(1024) k2_scan(
        const float* __restrict__ gamma, float* __restrict__ scal,
        const int* __restrict__ count, int* __restrict__ offs,
        int* __restrict__ cursor) {
    const int t = threadIdx.x;
    if (t == 0) {
        float sab = scal[0], saa = scal[1], sbb = scal[2];
        float na = sqrtf(saa); if (na < CS_EPS) na = CS_EPS;
        float nb = sqrtf(sbb); if (nb < CS_EPS) nb = CS_EPS;
        scal[3] = gamma[0] * (sab / (na * nb));
    }
    const int CH = (N_NODES + 1023) / 1024;  // 98
    const int base = t * CH;
    int lsum = 0;
    for (int i = 0; i < CH; i++) {
        int idx = base + i;
        if (idx < N_NODES) lsum += count[idx];
    }
    __shared__ int sc[1024];
    sc[t] = lsum;
    __syncthreads();
    for (int off = 1; off < 1024; off <<= 1) {
        int vv = (t >= off) ? sc[t - off] : 0;
        __syncthreads();
        sc[t] += vv;
        __syncthreads();
    }
    int run = sc[t] - lsum;  // exclusive prefix at chunk start
    for (int i = 0; i < CH; i++) {
        int idx = base + i;
        if (idx < N_NODES) {
            offs[idx] = run;
            cursor[idx] = run;
            run += count[idx];
        }
    }
    if (t == 1023) offs[N_NODES] = sc[1023];
}

// Scatter edges into row-sorted (CSR) order; fold c into adj.
__global__ void __launch_bounds__(256) k3_scatter(
        const int* __restrict__ row, const int* __restrict__ col,
        const float* __restrict__ adj, const float* __restrict__ s0,
        const float* __restrict__ scal, int* __restrict__ cursor,
        float2* __restrict__ ssa, int* __restrict__ scol) {
    int e = blockIdx.x * blockDim.x + threadIdx.x;
    if (e >= N_EDGES) return;
    float c = scal[3];
    int r = row[e];
    int pos = atomicAdd(&cursor[r], 1);
    ssa[pos] = make_float2(s0[e], adj[e] * c);
    scol[pos] = col[e];
}

// One wave per row: max -> exp/z + weighted v accumulation -> normalized store.
__global__ void __launch_bounds__(256) k4_out(
        const float* __restrict__ v, const int* __restrict__ offs,
        const float2* __restrict__ ssa, const int* __restrict__ scol,
        float* __restrict__ out) {
    const int tid  = threadIdx.x;
    const int lane = tid & 63;
    const int wid  = tid >> 6;
    const int r = blockIdx.x * 4 + wid;
    if (r >= N_NODES) return;
    const int start = offs[r], end = offs[r + 1];

    float lm0 = -INFINITY, lm1 = -INFINITY;
    for (int i = start + lane; i < end; i += 64) {
        float2 sa = ssa[i];
        lm0 = fmaxf(lm0, sa.x);
        lm1 = fmaxf(lm1, sa.y);
    }
#pragma unroll
    for (int off = 32; off >= 1; off >>= 1) {
        lm0 = fmaxf(lm0, __shfl_xor(lm0, off));
        lm1 = fmaxf(lm1, __shfl_xor(lm1, off));
    }

    float2 acc0 = make_float2(0.f, 0.f), acc1 = make_float2(0.f, 0.f);
    float lz0 = 0.f, lz1 = 0.f;
    for (int base = start; base < end; base += 64) {
        int i = base + lane;
        float w0 = 0.f, w1 = 0.f;
        int ci = 0;
        if (i < end) {
            float2 sa = ssa[i];
            w0 = expf(sa.x - lm0);
            w1 = expf(sa.y - lm1);
            ci = scol[i];
        }
        lz0 += w0; lz1 += w1;
        int cnt = min(64, end - base);
        for (int j = 0; j < cnt; j++) {
            float wj0 = __shfl(w0, j);
            float wj1 = __shfl(w1, j);
            int cj = __shfl(ci, j);
            float2 vv = ((const float2*)(v + (size_t)cj * DIM))[lane];
            acc0.x += wj0 * vv.x; acc0.y += wj0 * vv.y;
            acc1.x += wj1 * vv.x; acc1.y += wj1 * vv.y;
        }
    }
#pragma unroll
    for (int off = 32; off >= 1; off >>= 1) {
        lz0 += __shfl_xor(lz0, off);
        lz1 += __shfl_xor(lz1, off);
    }

    float2 o = make_float2(0.f, 0.f);
    if (end > start) {
        float iz0 = 1.0f / lz0, iz1 = 1.0f / lz1;
        o.x = 0.5f * (acc0.x * iz0 + acc1.x * iz1);
        o.y = 0.5f * (acc0.y * iz0 + acc1.y * iz1);
    }
    ((float2*)(out + (size_t)r * DIM))[lane] = o;
}

extern "C" void kernel_launch(void* const* d_in, const int* in_sizes, int n_in,
                              void* d_out, int out_size, void* d_ws, size_t ws_size,
                              hipStream_t stream) {
    const float* q        = (const float*)d_in[0];
    const float* k        = (const float*)d_in[1];
    const float* v        = (const float*)d_in[2];
    const float* eigs     = (const float*)d_in[3];
    const float* adj      = (const float*)d_in[4];
    const float* lambda0  = (const float*)d_in[5];
    const float* gamma    = (const float*)d_in[6];
    const float* motif_w  = (const float*)d_in[7];
    const int*   row      = (const int*)d_in[8];
    const int*   col      = (const int*)d_in[9];
    const int*   motif_ids= (const int*)d_in[10];
    float* out = (float*)d_out;

    char* ws = (char*)d_ws;
    float*  s0     = (float*)(ws + OFF_S0);
    float2* ssa    = (float2*)(ws + OFF_SA);
    int*    scol   = (int*)(ws + OFF_SCOL);
    int*    count  = (int*)(ws + OFF_COUNT);
    int*    offs   = (int*)(ws + OFF_OFFS);
    int*    cursor = (int*)(ws + OFF_CURSOR);
    float*  me     = (float*)(ws + OFF_ME);
    float*  scal   = (float*)(ws + OFF_SCAL);

    hipLaunchKernelGGL(k0_init, dim3((N_NODES + 255) / 256), dim3(256), 0, stream,
                       motif_w, motif_ids, me, count, scal);
    hipLaunchKernelGGL(k1_edge, dim3(4096), dim3(256), 0, stream,
                       q, k, eigs, lambda0, row, col, me, s0, count, scal);
    hipLaunchKernelGGL(k2_scan, dim3(1), dim3(1024), 0, stream,
                       gamma, scal, count, offs, cursor);
    hipLaunchKernelGGL(k3_scatter, dim3((N_EDGES + 255) / 256), dim3(256), 0, stream,
                       row, col, adj, s0, scal, cursor, ssa, scol);
    hipLaunchKernelGGL(k4_out, dim3((N_NODES + 3) / 4), dim3(256), 0, stream,
                       v, offs, ssa, scol, out);
}